// Round 7
// baseline (98.585 us; speedup 1.0000x reference)
//
#include <hip/hip_runtime.h>
#include <math.h>

#define MARGIN 0.3f
#define NJ 32   // column chunks (grid.y); chunk = 256 cols = 8 strips of 32

typedef short bf16x8 __attribute__((ext_vector_type(8)));
typedef float f32x4 __attribute__((ext_vector_type(4)));
typedef float f32x16 __attribute__((ext_vector_type(16)));
typedef unsigned int u32;
typedef const __attribute__((address_space(1))) u32* gp_t;
typedef __attribute__((address_space(3))) u32* lp_t;

__device__ __forceinline__ unsigned short f2bf_rne(float x) {
    unsigned b = __float_as_uint(x);
    unsigned r = b + 0x7FFFu + ((b >> 16) & 1u);
    return (unsigned short)(r >> 16);
}
__device__ __forceinline__ float bf2f(unsigned short h) {
    return __uint_as_float(((unsigned)h) << 16);
}
// family table {0,1,2,1,3,3} packed 2 bits/entry
__device__ __forceinline__ int fam_of(int lbl) { return (0xF64 >> (2 * lbl)) & 3; }

// ---------------- K1: deterministic counting sort by family ----------------
__global__ __launch_bounds__(1024) void sort_kernel(const int* __restrict__ labels,
                                                    int* __restrict__ posOf,
                                                    unsigned char* __restrict__ famSorted,
                                                    int* __restrict__ famLoHi, int B) {
    const int t = threadIdx.x;
    const int lane = t & 63, w = t >> 6;
    int lc[4] = {0, 0, 0, 0};
    int lf[8], lr[8];
#pragma unroll
    for (int j = 0; j < 8; j++) {
        int f = fam_of(labels[t * 8 + j]);
        lf[j] = f; lr[j] = lc[f]++;
    }
    int inc[4];
#pragma unroll
    for (int f = 0; f < 4; f++) {
        int v = lc[f];
#pragma unroll
        for (int o = 1; o < 64; o <<= 1) {
            int u = __shfl_up(v, o, 64);
            if (lane >= o) v += u;
        }
        inc[f] = v;
    }
    __shared__ int waveTot[16][4], waveBase[16][4], famBase[4], famTotS[4];
    if (lane == 63)
#pragma unroll
        for (int f = 0; f < 4; f++) waveTot[w][f] = inc[f];
    __syncthreads();
    if (t < 64) {
        int f = t >> 4, ww = t & 15;
        int v = waveTot[ww][f];
#pragma unroll
        for (int o = 1; o < 16; o <<= 1) {
            int u = __shfl_up(v, o, 64);
            if ((t & 15) >= o) v += u;
        }
        waveBase[ww][f] = v - waveTot[ww][f];
        if (ww == 15) famTotS[f] = v;
    }
    __syncthreads();
    if (t == 0) {
        int b = 0;
#pragma unroll
        for (int f = 0; f < 4; f++) {
            famBase[f] = b; famLoHi[f] = b; b += famTotS[f]; famLoHi[4 + f] = b;
        }
    }
    __syncthreads();
    int base[4];
#pragma unroll
    for (int f = 0; f < 4; f++) base[f] = famBase[f] + waveBase[w][f] + (inc[f] - lc[f]);
#pragma unroll
    for (int j = 0; j < 8; j++) {
        int pos = base[lf[j]] + lr[j];
        posOf[t * 8 + j] = pos;
        famSorted[pos] = (unsigned char)lf[j];
    }
}

// ---------------- K2: normalize + bf16 hi/lo split + 32-wide frag pack ----------------
// Pack layout for mfma_32x32x16 fragments, per 32-col strip (4096 shorts = 8KB):
//   addr = strip*4096 + kw*1024 + {hi:0, lo:512} + fl*8 + e
// where k = kw*16 + (fl>>5)*8 + e, col = fl&31.
// Fragment read = 16B at (lane*8 shorts): lane l -> col l&31, k-half l>>5.  [A and B
// use the SAME map, so the MFMA k-contraction is permutation-invariant.]
__global__ __launch_bounds__(256) void normpack_kernel(const float* __restrict__ emb,
                                                       const int* __restrict__ posOf,
                                                       short* __restrict__ pack, int B) {
    const int lane = threadIdx.x & 63;
    const int wid  = threadIdx.x >> 6;
    const int row  = blockIdx.x * 4 + wid;
    float x = emb[(size_t)row * 64 + lane];
    float ss = x * x;
#pragma unroll
    for (int o = 32; o > 0; o >>= 1) ss += __shfl_xor(ss, o, 64);
    float n = fmaxf(sqrtf(ss), 1e-12f);
    float v = x / n;
    unsigned short h = f2bf_rne(v);
    float lo = v - bf2f(h);
    unsigned short l = f2bf_rne(lo);
    int pos = posOf[row];
    int k = lane;
    int kw = k >> 4, kk = k & 15;
    int fl = (kk >> 3) * 32 + (pos & 31);
    size_t sidx = (size_t)(pos >> 5) * 4096 + (size_t)kw * 1024 + (size_t)fl * 8 + (kk & 7);
    pack[sidx] = (short)h;
    pack[sidx + 512] = (short)l;
}

// ---------------- K3: LDS-staged 32x32 MFMA GEMM + masked min/max ----------------
// Block: 256 rows x 256-col chunk. 4 waves; wave owns 64 rows = 2 strips of 32.
// B chunk (64KB, fragment-linear) staged once via global_load_lds; loop is pure
// LDS + MFMA. No source pipelining: 2 waves/SIMD co-scheduling hides ds_read.
__global__ __launch_bounds__(256) void gemm_minmax_kernel(
    const short* __restrict__ pack,
    const unsigned char* __restrict__ famSorted, const int* __restrict__ famLoHi,
    float* __restrict__ pMin, float* __restrict__ pMax, int B) {
    __shared__ short lds[32768];  // 64KB

    const int lane = threadIdx.x & 63;
    const int wid  = threadIdx.x >> 6;
    const int h    = lane >> 5;      // k-half / C row-half
    const int cc   = lane & 31;      // fragment column
    const int rowBase = blockIdx.x * 256 + wid * 64;
    const int aStrip0 = rowBase >> 5;  // 32-row strips
    const int jChunk0 = blockIdx.y * (B / NJ);
    const int jStrip0 = jChunk0 >> 5;

    // ---- stage B chunk: 64KB linear, wave w stages 16KB (16 x 1KB insts) ----
    {
        const char* src = (const char*)(pack + (size_t)jStrip0 * 4096);
#pragma unroll
        for (int i = 0; i < 16; i++) {
            int off = wid * 16384 + i * 1024;
            __builtin_amdgcn_global_load_lds((gp_t)(src + off + lane * 16),
                                             (lp_t)((char*)lds + off), 16, 0, 0);
        }
    }

    // ---- A fragments: 2 strips x 4 kw x (hi,lo) = 64 VGPRs, resident ----
    bf16x8 aHi[2][4], aLo[2][4];
#pragma unroll
    for (int s = 0; s < 2; s++) {
        const short* pA = pack + (size_t)(aStrip0 + s) * 4096;
#pragma unroll
        for (int kw = 0; kw < 4; kw++) {
            aHi[s][kw] = *(const bf16x8*)(pA + kw * 1024 + lane * 8);
            aLo[s][kw] = *(const bf16x8*)(pA + kw * 1024 + 512 + lane * 8);
        }
    }

    // ---- per-strip family classification (rows sorted) ----
    int sLo[2], sHi[2], sUni[2], sFam[2];
#pragma unroll
    for (int s = 0; s < 2; s++) {
        int f0  = famSorted[rowBase + s * 32];
        int f31 = famSorted[rowBase + s * 32 + 31];
        sUni[s] = __builtin_amdgcn_readfirstlane((f0 == f31) ? 1 : 0);
        sFam[s] = __builtin_amdgcn_readfirstlane(f0);
        sLo[s]  = __builtin_amdgcn_readfirstlane(famLoHi[f0]);
        sHi[s]  = __builtin_amdgcn_readfirstlane(famLoHi[4 + f0]);
    }

    f32x16 mn[2], mx[2];
#pragma unroll
    for (int s = 0; s < 2; s++)
#pragma unroll
        for (int r = 0; r < 16; r++) { mn[s][r] = 1e30f; mx[s][r] = -1e30f; }

    const f32x16 zq = {0.f};

    __syncthreads();  // staging complete (compiler drains vmcnt before barrier)

    // ---- sweep 8 j-tiles of 32 cols ----
    for (int jt = 0; jt < 8; jt++) {
        const int j0 = jChunk0 + jt * 32;
        const short* pB = lds + jt * 4096;
        bf16x8 bHi[4], bLo[4];
#pragma unroll
        for (int kw = 0; kw < 4; kw++) {
            bHi[kw] = *(const bf16x8*)(pB + kw * 1024 + lane * 8);
            bLo[kw] = *(const bf16x8*)(pB + kw * 1024 + 512 + lane * 8);
        }
#pragma unroll
        for (int s = 0; s < 2; s++) {
            // two independent 6-chains: p = hh(4)+hl(2), q = lh(4)+hl(2)
            f32x16 p, q;
            p = __builtin_amdgcn_mfma_f32_32x32x16_bf16(aHi[s][0], bHi[0], zq, 0, 0, 0);
            q = __builtin_amdgcn_mfma_f32_32x32x16_bf16(aLo[s][0], bHi[0], zq, 0, 0, 0);
            p = __builtin_amdgcn_mfma_f32_32x32x16_bf16(aHi[s][1], bHi[1], p, 0, 0, 0);
            q = __builtin_amdgcn_mfma_f32_32x32x16_bf16(aLo[s][1], bHi[1], q, 0, 0, 0);
            p = __builtin_amdgcn_mfma_f32_32x32x16_bf16(aHi[s][2], bHi[2], p, 0, 0, 0);
            q = __builtin_amdgcn_mfma_f32_32x32x16_bf16(aLo[s][2], bHi[2], q, 0, 0, 0);
            p = __builtin_amdgcn_mfma_f32_32x32x16_bf16(aHi[s][3], bHi[3], p, 0, 0, 0);
            q = __builtin_amdgcn_mfma_f32_32x32x16_bf16(aLo[s][3], bHi[3], q, 0, 0, 0);
            p = __builtin_amdgcn_mfma_f32_32x32x16_bf16(aHi[s][0], bLo[0], p, 0, 0, 0);
            q = __builtin_amdgcn_mfma_f32_32x32x16_bf16(aHi[s][2], bLo[2], q, 0, 0, 0);
            p = __builtin_amdgcn_mfma_f32_32x32x16_bf16(aHi[s][1], bLo[1], p, 0, 0, 0);
            q = __builtin_amdgcn_mfma_f32_32x32x16_bf16(aHi[s][3], bLo[3], q, 0, 0, 0);
            f32x16 acc = p + q;

            if (sUni[s] && j0 >= sLo[s] && j0 + 32 <= sHi[s]) {
                // fully same-family (diagonal dot==1 can never be the min)
#pragma unroll
                for (int r = 0; r < 16; r++) mn[s][r] = fminf(mn[s][r], acc[r]);
            } else if (sUni[s] && (j0 >= sHi[s] || j0 + 32 <= sLo[s])) {
                // fully different-family
#pragma unroll
                for (int r = 0; r < 16; r++) mx[s][r] = fmaxf(mx[s][r], acc[r]);
            } else if (sUni[s]) {
                // uniform rows, mixed cols: per-col compare
                int fj = famSorted[j0 + cc];
                bool same = (fj == sFam[s]);
#pragma unroll
                for (int r = 0; r < 16; r++) {
                    mn[s][r] = fminf(mn[s][r], same ? acc[r] : 1e30f);
                    mx[s][r] = fmaxf(mx[s][r], same ? -1e30f : acc[r]);
                }
            } else {
                // rare: strip spans a family boundary — per-element compare
                int fj = famSorted[j0 + cc];
                int sRow = rowBase + s * 32;
#pragma unroll
                for (int r = 0; r < 16; r++) {
                    int fi = famSorted[sRow + (r & 3) + 8 * (r >> 2) + 4 * h];
                    bool same = (fi == fj);
                    mn[s][r] = fminf(mn[s][r], same ? acc[r] : 1e30f);
                    mx[s][r] = fmaxf(mx[s][r], same ? -1e30f : acc[r]);
                }
            }
        }
    }

    // ---- reduce across 32 column-lanes (within each half), write per-row ----
#pragma unroll
    for (int s = 0; s < 2; s++) {
        int sRow = rowBase + s * 32;
#pragma unroll
        for (int r = 0; r < 16; r++) {
            float mnv = mn[s][r], mxv = mx[s][r];
#pragma unroll
            for (int o = 16; o > 0; o >>= 1) {
                mnv = fminf(mnv, __shfl_xor(mnv, o, 64));
                mxv = fmaxf(mxv, __shfl_xor(mxv, o, 64));
            }
            if (cc == 0) {
                int row = sRow + (r & 3) + 8 * (r >> 2) + 4 * h;  // sorted-row idx
                pMin[(size_t)blockIdx.y * B + row] = mnv;
                pMax[(size_t)blockIdx.y * B + row] = mxv;
            }
        }
    }
}

// ---------------- K4: per-row chunk combine + block partial sums ----------------
__global__ __launch_bounds__(256) void rowloss_kernel(const float* __restrict__ pMin,
                                                      const float* __restrict__ pMax,
                                                      float* __restrict__ partial, int B) {
    const int row = blockIdx.x * 256 + threadIdx.x;
    float mn = 1e30f, mx = -1e30f;
#pragma unroll 4
    for (int cn = 0; cn < NJ; cn++) {
        mn = fminf(mn, pMin[(size_t)cn * B + row]);
        mx = fmaxf(mx, pMax[(size_t)cn * B + row]);
    }
    float sum = 0.f, cnt = 0.f;
    if (mn < 1e29f && mx > -1e29f) {
        sum = fmaxf(mx - mn + MARGIN, 0.f);
        cnt = 1.f;
    }
#pragma unroll
    for (int o = 32; o > 0; o >>= 1) {
        sum += __shfl_xor(sum, o, 64);
        cnt += __shfl_xor(cnt, o, 64);
    }
    __shared__ float sS[4], sC[4];
    const int lane = threadIdx.x & 63, w = threadIdx.x >> 6;
    if (lane == 0) { sS[w] = sum; sC[w] = cnt; }
    __syncthreads();
    if (threadIdx.x == 0) {
        partial[blockIdx.x]      = sS[0] + sS[1] + sS[2] + sS[3];
        partial[64 + blockIdx.x] = sC[0] + sC[1] + sC[2] + sC[3];
    }
}

// ---------------- K5: deterministic final reduce ----------------
__global__ void final_kernel(const float* __restrict__ partial, float* __restrict__ out, int nb) {
    if (threadIdx.x == 0) {
        float S = 0.f, C = 0.f;
        for (int i = 0; i < nb; i++) { S += partial[i]; C += partial[64 + i]; }
        out[0] = S / fmaxf(C, 1.f);
    }
}

extern "C" void kernel_launch(void* const* d_in, const int* in_sizes, int n_in,
                              void* d_out, int out_size, void* d_ws, size_t ws_size,
                              hipStream_t stream) {
    const float* emb    = (const float*)d_in[0];
    const int*   labels = (const int*)d_in[1];
    const int B = in_sizes[1];  // 8192, D == 64

    char* base = (char*)d_ws;
    size_t off = 0;
    auto alloc = [&](size_t bytes) -> char* {
        char* p = base + off;
        off = (off + bytes + 255) & ~(size_t)255;
        return p;
    };
    int*           posOf     = (int*)alloc((size_t)B * 4);
    unsigned char* famSorted = (unsigned char*)alloc((size_t)B);
    int*           famLoHi   = (int*)alloc(32);
    short*         pack      = (short*)alloc((size_t)B * 256);   // 2MB: hi+lo frag pack
    float*         pMin      = (float*)alloc((size_t)NJ * B * 4);
    float*         pMax      = (float*)alloc((size_t)NJ * B * 4);
    float*         partial   = (float*)alloc(128 * 4);

    sort_kernel<<<1, 1024, 0, stream>>>(labels, posOf, famSorted, famLoHi, B);
    normpack_kernel<<<B / 4, 256, 0, stream>>>(emb, posOf, pack, B);
    dim3 g3(B / 256, NJ);
    gemm_minmax_kernel<<<g3, 256, 0, stream>>>(pack, famSorted, famLoHi, pMin, pMax, B);
    rowloss_kernel<<<B / 256, 256, 0, stream>>>(pMin, pMax, partial, B);
    final_kernel<<<1, 64, 0, stream>>>(partial, (float*)d_out, B / 256);
}

// Round 8
// 54.149 us; speedup vs baseline: 1.8206x; 1.8206x over previous
//
#include <hip/hip_runtime.h>
#include <math.h>

#define MARGIN 0.3f
#define NJ 64   // column chunks (grid.y); chunk = 128 cols = 8 tiles of 16

typedef short bf16x8 __attribute__((ext_vector_type(8)));
typedef float f32x4 __attribute__((ext_vector_type(4)));

__device__ __forceinline__ unsigned short f2bf_rne(float x) {
    unsigned b = __float_as_uint(x);
    unsigned r = b + 0x7FFFu + ((b >> 16) & 1u);
    return (unsigned short)(r >> 16);
}
// family table {0,1,2,1,3,3} packed 2 bits/entry
__device__ __forceinline__ int fam_of(int lbl) { return (0xF64 >> (2 * lbl)) & 3; }

// ---------------- K1: deterministic counting sort by family ----------------
__global__ __launch_bounds__(1024) void sort_kernel(const int* __restrict__ labels,
                                                    int* __restrict__ posOf,
                                                    unsigned char* __restrict__ famSorted,
                                                    int* __restrict__ famLoHi, int B) {
    const int t = threadIdx.x;
    const int lane = t & 63, w = t >> 6;
    int lc[4] = {0, 0, 0, 0};
    int lf[8], lr[8];
#pragma unroll
    for (int j = 0; j < 8; j++) {
        int f = fam_of(labels[t * 8 + j]);
        lf[j] = f; lr[j] = lc[f]++;
    }
    int inc[4];
#pragma unroll
    for (int f = 0; f < 4; f++) {
        int v = lc[f];
#pragma unroll
        for (int o = 1; o < 64; o <<= 1) {
            int u = __shfl_up(v, o, 64);
            if (lane >= o) v += u;
        }
        inc[f] = v;
    }
    __shared__ int waveTot[16][4], waveBase[16][4], famBase[4], famTotS[4];
    if (lane == 63)
#pragma unroll
        for (int f = 0; f < 4; f++) waveTot[w][f] = inc[f];
    __syncthreads();
    if (t < 64) {
        int f = t >> 4, ww = t & 15;
        int v = waveTot[ww][f];
#pragma unroll
        for (int o = 1; o < 16; o <<= 1) {
            int u = __shfl_up(v, o, 64);
            if ((t & 15) >= o) v += u;
        }
        waveBase[ww][f] = v - waveTot[ww][f];
        if (ww == 15) famTotS[f] = v;
    }
    __syncthreads();
    if (t == 0) {
        int b = 0;
#pragma unroll
        for (int f = 0; f < 4; f++) {
            famBase[f] = b; famLoHi[f] = b; b += famTotS[f]; famLoHi[4 + f] = b;
        }
    }
    __syncthreads();
    int base[4];
#pragma unroll
    for (int f = 0; f < 4; f++) base[f] = famBase[f] + waveBase[w][f] + (inc[f] - lc[f]);
#pragma unroll
    for (int j = 0; j < 8; j++) {
        int pos = base[lf[j]] + lr[j];
        posOf[t * 8 + j] = pos;
        famSorted[pos] = (unsigned char)lf[j];
    }
}

// ---------------- K2: normalize + bf16 round + packed scatter (hi only) ----------------
// pack layout (bf16 elems): idx = strip*1024 + (k>>3)*128 + (pos&15)*8 + (k&7)
// Fragment read: lane l takes 16B at strip*1024 + kwin*512 + l*8 ->
// col = l&15, k = kwin*32 + (l>>4)*8 + e.  A and B use the SAME lane->(col,k)
// map, so the MFMA k-contraction is permutation-invariant (verified absmax 0.0
// with this map in R2).
__global__ __launch_bounds__(256) void normpack_kernel(const float* __restrict__ emb,
                                                       const int* __restrict__ posOf,
                                                       short* __restrict__ pack, int B) {
    const int lane = threadIdx.x & 63;
    const int wid  = threadIdx.x >> 6;
    const int row  = blockIdx.x * 4 + wid;
    float x = emb[(size_t)row * 64 + lane];
    float ss = x * x;
#pragma unroll
    for (int o = 32; o > 0; o >>= 1) ss += __shfl_xor(ss, o, 64);
    float n = fmaxf(sqrtf(ss), 1e-12f);
    float v = x / n;
    unsigned short h = f2bf_rne(v);
    int pos = posOf[row];
    size_t idx = (size_t)(pos >> 4) * 1024 + (size_t)(lane >> 3) * 128 + (size_t)(pos & 15) * 8 + (lane & 7);
    pack[idx] = (short)h;
}

// ---------------- K3: bf16 MFMA GEMM + masked min/max (plain, no LDS) ----------------
// 4 waves/block, 64 rows/wave (4 strips of 16), j-chunk of 128 cols (8 tiles).
// 2 MFMA per strip-tile; pure-hi bf16 (error ~1e-3 on the loss, threshold 2.3e-2).
__global__ __launch_bounds__(256) void gemm_minmax_kernel(
    const short* __restrict__ pack,
    const unsigned char* __restrict__ famSorted, const int* __restrict__ famLoHi,
    float* __restrict__ pMin, float* __restrict__ pMax, int B) {
    const int lane = threadIdx.x & 63;
    const int wid  = threadIdx.x >> 6;
    const int g = lane >> 4;
    const int c = lane & 15;
    const int rowBase = blockIdx.x * 256 + wid * 64;
    const int aStrip0 = rowBase >> 4;

    // A fragments: 4 strips x 2 k-windows = 32 VGPRs, resident all sweep.
    bf16x8 aH[4][2];
#pragma unroll
    for (int s = 0; s < 4; s++) {
        const short* pA = pack + (size_t)(aStrip0 + s) * 1024;
        aH[s][0] = *(const bf16x8*)(pA + lane * 8);
        aH[s][1] = *(const bf16x8*)(pA + 512 + lane * 8);
    }

    // Per-strip family classification (rows sorted -> piecewise constant).
    int sLo[4], sHi[4], sUni[4];
#pragma unroll
    for (int s = 0; s < 4; s++) {
        int f0  = famSorted[rowBase + s * 16];
        int f15 = famSorted[rowBase + s * 16 + 15];
        sUni[s] = __builtin_amdgcn_readfirstlane((f0 == f15) ? 1 : 0);
        sLo[s]  = __builtin_amdgcn_readfirstlane(famLoHi[f0]);
        sHi[s]  = __builtin_amdgcn_readfirstlane(famLoHi[4 + f0]);
    }

    const f32x4 zq = {0.f, 0.f, 0.f, 0.f};
    f32x4 mn[4], mx[4];
#pragma unroll
    for (int s = 0; s < 4; s++)
#pragma unroll
        for (int r = 0; r < 4; r++) { mn[s][r] = 1e30f; mx[s][r] = -1e30f; }

    const int jChunk0 = blockIdx.y * (B / NJ);
    const int jStrip0 = jChunk0 >> 4;
    const int NJT = (B / NJ) >> 4;  // 8

    for (int jt = 0; jt < NJT; jt++) {
        const int j0 = jChunk0 + jt * 16;
        const short* pB = pack + (size_t)(jStrip0 + jt) * 1024;
        bf16x8 bh0 = *(const bf16x8*)(pB + lane * 8);
        bf16x8 bh1 = *(const bf16x8*)(pB + 512 + lane * 8);

#pragma unroll
        for (int s = 0; s < 4; s++) {
            f32x4 acc;
            acc = __builtin_amdgcn_mfma_f32_16x16x32_bf16(aH[s][0], bh0, zq, 0, 0, 0);
            acc = __builtin_amdgcn_mfma_f32_16x16x32_bf16(aH[s][1], bh1, acc, 0, 0, 0);

            if (sUni[s] && j0 >= sLo[s] && j0 + 16 <= sHi[s]) {
                // fully same-family (diagonal dot ~1 is the max dot, never the min)
#pragma unroll
                for (int r = 0; r < 4; r++) mn[s][r] = fminf(mn[s][r], acc[r]);
            } else if (sUni[s] && (j0 >= sHi[s] || j0 + 16 <= sLo[s])) {
                // fully different-family
#pragma unroll
                for (int r = 0; r < 4; r++) mx[s][r] = fmaxf(mx[s][r], acc[r]);
            } else {
                // boundary tile: per-element family compare
                int fj = famSorted[j0 + c];
                unsigned fi4 = *(const unsigned*)(famSorted + rowBase + s * 16 + g * 4);
#pragma unroll
                for (int r = 0; r < 4; r++) {
                    int fir = (int)((fi4 >> (8 * r)) & 255u);
                    bool same = (fir == fj);
                    float d = acc[r];
                    mn[s][r] = fminf(mn[s][r], same ? d : 1e30f);
                    mx[s][r] = fmaxf(mx[s][r], same ? -1e30f : d);
                }
            }
        }
    }

    // Reduce across the 16 column-lanes (same g), then write per-row partials.
#pragma unroll
    for (int s = 0; s < 4; s++)
#pragma unroll
        for (int r = 0; r < 4; r++) {
            float mnv = mn[s][r], mxv = mx[s][r];
#pragma unroll
            for (int o = 8; o > 0; o >>= 1) {
                mnv = fminf(mnv, __shfl_xor(mnv, o, 64));
                mxv = fmaxf(mxv, __shfl_xor(mxv, o, 64));
            }
            if (c == 0) {
                int row = rowBase + s * 16 + g * 4 + r;  // sorted-row index
                pMin[(size_t)blockIdx.y * B + row] = mnv;
                pMax[(size_t)blockIdx.y * B + row] = mxv;
            }
        }
}

// ---------------- K4: per-row chunk combine + block partial sums ----------------
__global__ __launch_bounds__(256) void rowloss_kernel(const float* __restrict__ pMin,
                                                      const float* __restrict__ pMax,
                                                      float* __restrict__ partial, int B) {
    const int row = blockIdx.x * 256 + threadIdx.x;
    float mn = 1e30f, mx = -1e30f;
#pragma unroll 8
    for (int cn = 0; cn < NJ; cn++) {
        mn = fminf(mn, pMin[(size_t)cn * B + row]);
        mx = fmaxf(mx, pMax[(size_t)cn * B + row]);
    }
    float sum = 0.f, cnt = 0.f;
    if (mn < 1e29f && mx > -1e29f) {  // has same && has diff
        sum = fmaxf(mx - mn + MARGIN, 0.f);  // relu(d_pos - d_neg + margin)
        cnt = 1.f;
    }
#pragma unroll
    for (int o = 32; o > 0; o >>= 1) {
        sum += __shfl_xor(sum, o, 64);
        cnt += __shfl_xor(cnt, o, 64);
    }
    __shared__ float sS[4], sC[4];
    const int lane = threadIdx.x & 63, w = threadIdx.x >> 6;
    if (lane == 0) { sS[w] = sum; sC[w] = cnt; }
    __syncthreads();
    if (threadIdx.x == 0) {
        partial[blockIdx.x]      = sS[0] + sS[1] + sS[2] + sS[3];
        partial[64 + blockIdx.x] = sC[0] + sC[1] + sC[2] + sC[3];
    }
}

// ---------------- K5: deterministic final reduce ----------------
__global__ void final_kernel(const float* __restrict__ partial, float* __restrict__ out, int nb) {
    if (threadIdx.x == 0) {
        float S = 0.f, C = 0.f;
        for (int i = 0; i < nb; i++) { S += partial[i]; C += partial[64 + i]; }
        out[0] = S / fmaxf(C, 1.f);
    }
}

extern "C" void kernel_launch(void* const* d_in, const int* in_sizes, int n_in,
                              void* d_out, int out_size, void* d_ws, size_t ws_size,
                              hipStream_t stream) {
    const float* emb    = (const float*)d_in[0];
    const int*   labels = (const int*)d_in[1];
    const int B = in_sizes[1];  // 8192, D == 64

    char* base = (char*)d_ws;
    size_t off = 0;
    auto alloc = [&](size_t bytes) -> char* {
        char* p = base + off;
        off = (off + bytes + 255) & ~(size_t)255;
        return p;
    };
    int*           posOf     = (int*)alloc((size_t)B * 4);
    unsigned char* famSorted = (unsigned char*)alloc((size_t)B);
    int*           famLoHi   = (int*)alloc(32);
    short*         pack      = (short*)alloc((size_t)B * 64 * 2);  // hi-only, 1MB
    float*         pMin      = (float*)alloc((size_t)NJ * B * 4);
    float*         pMax      = (float*)alloc((size_t)NJ * B * 4);
    float*         partial   = (float*)alloc(128 * 4);

    sort_kernel<<<1, 1024, 0, stream>>>(labels, posOf, famSorted, famLoHi, B);
    normpack_kernel<<<B / 4, 256, 0, stream>>>(emb, posOf, pack, B);
    dim3 g3(B / 256, NJ);
    gemm_minmax_kernel<<<g3, 256, 0, stream>>>(pack, famSorted, famLoHi, pMin, pMax, B);
    rowloss_kernel<<<B / 256, 256, 0, stream>>>(pMin, pMax, partial, B);
    final_kernel<<<1, 64, 0, stream>>>(partial, (float*)d_out, B / 256);
}

// Round 9
// 46.780 us; speedup vs baseline: 2.1074x; 1.1575x over previous
//
#include <hip/hip_runtime.h>
#include <math.h>

#define MARGIN 0.3f
#define NJ 64        // column chunks; chunk = 128 cols = 4 pairs of 16x2
#define NPAIR 4      // compile-time: (8192/NJ)/32

typedef short bf16x8 __attribute__((ext_vector_type(8)));
typedef float f32x4 __attribute__((ext_vector_type(4)));

__device__ __forceinline__ unsigned short f2bf_rne(float x) {
    unsigned b = __float_as_uint(x);
    unsigned r = b + 0x7FFFu + ((b >> 16) & 1u);
    return (unsigned short)(r >> 16);
}
// family table {0,1,2,1,3,3} packed 2 bits/entry
__device__ __forceinline__ int fam_of(int lbl) { return (0xF64 >> (2 * lbl)) & 3; }

// ---------------- K1: deterministic counting sort by family ----------------
__global__ __launch_bounds__(1024) void sort_kernel(const int* __restrict__ labels,
                                                    int* __restrict__ posOf,
                                                    unsigned char* __restrict__ famSorted,
                                                    int* __restrict__ famLoHi, int B) {
    const int t = threadIdx.x;
    const int lane = t & 63, w = t >> 6;
    int lc[4] = {0, 0, 0, 0};
    int lf[8], lr[8];
#pragma unroll
    for (int j = 0; j < 8; j++) {
        int f = fam_of(labels[t * 8 + j]);
        lf[j] = f; lr[j] = lc[f]++;
    }
    int inc[4];
#pragma unroll
    for (int f = 0; f < 4; f++) {
        int v = lc[f];
#pragma unroll
        for (int o = 1; o < 64; o <<= 1) {
            int u = __shfl_up(v, o, 64);
            if (lane >= o) v += u;
        }
        inc[f] = v;
    }
    __shared__ int waveTot[16][4], waveBase[16][4], famBase[4], famTotS[4];
    if (lane == 63)
#pragma unroll
        for (int f = 0; f < 4; f++) waveTot[w][f] = inc[f];
    __syncthreads();
    if (t < 64) {
        int f = t >> 4, ww = t & 15;
        int v = waveTot[ww][f];
#pragma unroll
        for (int o = 1; o < 16; o <<= 1) {
            int u = __shfl_up(v, o, 64);
            if ((t & 15) >= o) v += u;
        }
        waveBase[ww][f] = v - waveTot[ww][f];
        if (ww == 15) famTotS[f] = v;
    }
    __syncthreads();
    if (t == 0) {
        int b = 0;
#pragma unroll
        for (int f = 0; f < 4; f++) {
            famBase[f] = b; famLoHi[f] = b; b += famTotS[f]; famLoHi[4 + f] = b;
        }
    }
    __syncthreads();
    int base[4];
#pragma unroll
    for (int f = 0; f < 4; f++) base[f] = famBase[f] + waveBase[w][f] + (inc[f] - lc[f]);
#pragma unroll
    for (int j = 0; j < 8; j++) {
        int pos = base[lf[j]] + lr[j];
        posOf[t * 8 + j] = pos;
        famSorted[pos] = (unsigned char)lf[j];
    }
}

// ---------------- K2: normalize + bf16 round + packed scatter (hi only) ----------------
// pack layout: idx = strip*1024 + (k>>3)*128 + (pos&15)*8 + (k&7).
// Fragment read: 16B at strip*1024 + kwin*512 + lane*8. A and B share the map,
// so the MFMA k-contraction is permutation-invariant (absmax-verified R2/R8).
__global__ __launch_bounds__(256) void normpack_kernel(const float* __restrict__ emb,
                                                       const int* __restrict__ posOf,
                                                       short* __restrict__ pack, int B) {
    const int lane = threadIdx.x & 63;
    const int wid  = threadIdx.x >> 6;
    const int row  = blockIdx.x * 4 + wid;
    float x = emb[(size_t)row * 64 + lane];
    float ss = x * x;
#pragma unroll
    for (int o = 32; o > 0; o >>= 1) ss += __shfl_xor(ss, o, 64);
    float n = fmaxf(sqrtf(ss), 1e-12f);
    unsigned short h = f2bf_rne(x / n);
    int pos = posOf[row];
    size_t idx = (size_t)(pos >> 4) * 1024 + (size_t)(lane >> 3) * 128 + (size_t)(pos & 15) * 8 + (lane & 7);
    pack[idx] = (short)h;
}

// ---------------- K3: bf16 MFMA GEMM + paired masked min/max ----------------
// 4 waves/block, 64 rows/wave (4 strips of 16), chunk = 128 cols = 4 tile-pairs.
// Fully unrolled (compile-time trips) so the compiler batches loads; pairs of
// same-class tiles fold into min3/max3 (0.5 VALU op per dot).
__global__ __launch_bounds__(256) void gemm_minmax_kernel(
    const short* __restrict__ pack,
    const unsigned char* __restrict__ famSorted, const int* __restrict__ famLoHi,
    float* __restrict__ pMin, float* __restrict__ pMax, int B) {
    const int lane = threadIdx.x & 63;
    const int wid  = threadIdx.x >> 6;
    const int g = lane >> 4;
    const int c = lane & 15;
    const int rowBase = blockIdx.x * 256 + wid * 64;
    const int aStrip0 = rowBase >> 4;

    // A fragments: 4 strips x 2 k-windows = 32 VGPRs, resident all sweep.
    bf16x8 aH[4][2];
#pragma unroll
    for (int s = 0; s < 4; s++) {
        const short* pA = pack + (size_t)(aStrip0 + s) * 1024;
        aH[s][0] = *(const bf16x8*)(pA + lane * 8);
        aH[s][1] = *(const bf16x8*)(pA + 512 + lane * 8);
    }

    // Per-strip family classification (rows sorted -> piecewise constant).
    int sLo[4], sHi[4], sUni[4];
#pragma unroll
    for (int s = 0; s < 4; s++) {
        int f0  = famSorted[rowBase + s * 16];
        int f15 = famSorted[rowBase + s * 16 + 15];
        sUni[s] = __builtin_amdgcn_readfirstlane((f0 == f15) ? 1 : 0);
        sLo[s]  = __builtin_amdgcn_readfirstlane(famLoHi[f0]);
        sHi[s]  = __builtin_amdgcn_readfirstlane(famLoHi[4 + f0]);
    }

    const f32x4 zq = {0.f, 0.f, 0.f, 0.f};
    f32x4 mn[4], mx[4];
#pragma unroll
    for (int s = 0; s < 4; s++)
#pragma unroll
        for (int r = 0; r < 4; r++) { mn[s][r] = 1e30f; mx[s][r] = -1e30f; }

    const int jChunk0 = blockIdx.y * 128;
    const int jStrip0 = jChunk0 >> 4;
    const short* pBbase = pack + (size_t)jStrip0 * 1024;

#pragma unroll
    for (int jp = 0; jp < NPAIR; jp++) {
        const int j0 = jChunk0 + jp * 32;
        const short* pB0 = pBbase + (size_t)(2 * jp) * 1024;
        const short* pB1 = pB0 + 1024;
        bf16x8 b0h0 = *(const bf16x8*)(pB0 + lane * 8);
        bf16x8 b0h1 = *(const bf16x8*)(pB0 + 512 + lane * 8);
        bf16x8 b1h0 = *(const bf16x8*)(pB1 + lane * 8);
        bf16x8 b1h1 = *(const bf16x8*)(pB1 + 512 + lane * 8);

#pragma unroll
        for (int s = 0; s < 4; s++) {
            f32x4 accA, accB;
            accA = __builtin_amdgcn_mfma_f32_16x16x32_bf16(aH[s][0], b0h0, zq, 0, 0, 0);
            accB = __builtin_amdgcn_mfma_f32_16x16x32_bf16(aH[s][0], b1h0, zq, 0, 0, 0);
            accA = __builtin_amdgcn_mfma_f32_16x16x32_bf16(aH[s][1], b0h1, accA, 0, 0, 0);
            accB = __builtin_amdgcn_mfma_f32_16x16x32_bf16(aH[s][1], b1h1, accB, 0, 0, 0);

            if (sUni[s] && j0 >= sLo[s] && j0 + 32 <= sHi[s]) {
                // both tiles fully same-family -> v_min3 (diag dot~1 never the min)
#pragma unroll
                for (int r = 0; r < 4; r++)
                    mn[s][r] = fminf(fminf(mn[s][r], accA[r]), accB[r]);
            } else if (sUni[s] && (j0 >= sHi[s] || j0 + 32 <= sLo[s])) {
                // both tiles fully different-family -> v_max3
#pragma unroll
                for (int r = 0; r < 4; r++)
                    mx[s][r] = fmaxf(fmaxf(mx[s][r], accA[r]), accB[r]);
            } else {
                // rare: pair spans a family boundary -> per-element compare
                int fjA = famSorted[j0 + c];
                int fjB = famSorted[j0 + 16 + c];
                unsigned fi4 = *(const unsigned*)(famSorted + rowBase + s * 16 + g * 4);
#pragma unroll
                for (int r = 0; r < 4; r++) {
                    int fir = (int)((fi4 >> (8 * r)) & 255u);
                    bool sameA = (fir == fjA), sameB = (fir == fjB);
                    mn[s][r] = fminf(mn[s][r], sameA ? accA[r] : 1e30f);
                    mx[s][r] = fmaxf(mx[s][r], sameA ? -1e30f : accA[r]);
                    mn[s][r] = fminf(mn[s][r], sameB ? accB[r] : 1e30f);
                    mx[s][r] = fmaxf(mx[s][r], sameB ? -1e30f : accB[r]);
                }
            }
        }
    }

    // Reduce across the 16 column-lanes (same g), then write per-row partials.
#pragma unroll
    for (int s = 0; s < 4; s++)
#pragma unroll
        for (int r = 0; r < 4; r++) {
            float mnv = mn[s][r], mxv = mx[s][r];
#pragma unroll
            for (int o = 8; o > 0; o >>= 1) {
                mnv = fminf(mnv, __shfl_xor(mnv, o, 64));
                mxv = fmaxf(mxv, __shfl_xor(mxv, o, 64));
            }
            if (c == 0) {
                int row = rowBase + s * 16 + g * 4 + r;  // sorted-row index
                pMin[(size_t)blockIdx.y * B + row] = mnv;
                pMax[(size_t)blockIdx.y * B + row] = mxv;
            }
        }
}

// ---------------- K4: per-row chunk combine + block partial sums ----------------
__global__ __launch_bounds__(256) void rowloss_kernel(const float* __restrict__ pMin,
                                                      const float* __restrict__ pMax,
                                                      float* __restrict__ partial, int B) {
    const int row = blockIdx.x * 256 + threadIdx.x;
    float mn = 1e30f, mx = -1e30f;
#pragma unroll 8
    for (int cn = 0; cn < NJ; cn++) {
        mn = fminf(mn, pMin[(size_t)cn * B + row]);
        mx = fmaxf(mx, pMax[(size_t)cn * B + row]);
    }
    float sum = 0.f, cnt = 0.f;
    if (mn < 1e29f && mx > -1e29f) {  // has same && has diff
        sum = fmaxf(mx - mn + MARGIN, 0.f);  // relu(d_pos - d_neg + margin)
        cnt = 1.f;
    }
#pragma unroll
    for (int o = 32; o > 0; o >>= 1) {
        sum += __shfl_xor(sum, o, 64);
        cnt += __shfl_xor(cnt, o, 64);
    }
    __shared__ float sS[4], sC[4];
    const int lane = threadIdx.x & 63, w = threadIdx.x >> 6;
    if (lane == 0) { sS[w] = sum; sC[w] = cnt; }
    __syncthreads();
    if (threadIdx.x == 0) {
        partial[blockIdx.x]      = sS[0] + sS[1] + sS[2] + sS[3];
        partial[64 + blockIdx.x] = sC[0] + sC[1] + sC[2] + sC[3];
    }
}

// ---------------- K5: deterministic final reduce ----------------
__global__ void final_kernel(const float* __restrict__ partial, float* __restrict__ out, int nb) {
    if (threadIdx.x == 0) {
        float S = 0.f, C = 0.f;
        for (int i = 0; i < nb; i++) { S += partial[i]; C += partial[64 + i]; }
        out[0] = S / fmaxf(C, 1.f);
    }
}

extern "C" void kernel_launch(void* const* d_in, const int* in_sizes, int n_in,
                              void* d_out, int out_size, void* d_ws, size_t ws_size,
                              hipStream_t stream) {
    const float* emb    = (const float*)d_in[0];
    const int*   labels = (const int*)d_in[1];
    const int B = in_sizes[1];  // 8192, D == 64

    char* base = (char*)d_ws;
    size_t off = 0;
    auto alloc = [&](size_t bytes) -> char* {
        char* p = base + off;
        off = (off + bytes + 255) & ~(size_t)255;
        return p;
    };
    int*           posOf     = (int*)alloc((size_t)B * 4);
    unsigned char* famSorted = (unsigned char*)alloc((size_t)B);
    int*           famLoHi   = (int*)alloc(32);
    short*         pack      = (short*)alloc((size_t)B * 64 * 2);  // hi-only, 1MB
    float*         pMin      = (float*)alloc((size_t)NJ * B * 4);
    float*         pMax      = (float*)alloc((size_t)NJ * B * 4);
    float*         partial   = (float*)alloc(128 * 4);

    sort_kernel<<<1, 1024, 0, stream>>>(labels, posOf, famSorted, famLoHi, B);
    normpack_kernel<<<B / 4, 256, 0, stream>>>(emb, posOf, pack, B);
    dim3 g3(B / 256, NJ);
    gemm_minmax_kernel<<<g3, 256, 0, stream>>>(pack, famSorted, famLoHi, pMin, pMax, B);
    rowloss_kernel<<<B / 256, 256, 0, stream>>>(pMin, pMax, partial, B);
    final_kernel<<<1, 64, 0, stream>>>(partial, (float*)d_out, B / 256);
}

// Round 10
// 33.783 us; speedup vs baseline: 2.9182x; 1.3847x over previous
//
#include <hip/hip_runtime.h>
#include <math.h>

#define MARGIN 0.3f
#define NJ 64        // column chunks; chunk = 128 cols = 4 pairs of 16x2
#define NPAIR 4      // compile-time: (8192/NJ)/32

typedef short bf16x8 __attribute__((ext_vector_type(8)));
typedef float f32x4 __attribute__((ext_vector_type(4)));

__device__ __forceinline__ unsigned short f2bf_rne(float x) {
    unsigned b = __float_as_uint(x);
    unsigned r = b + 0x7FFFu + ((b >> 16) & 1u);
    return (unsigned short)(r >> 16);
}
// family table {0,1,2,1,3,3} packed 2 bits/entry
__device__ __forceinline__ int fam_of(int lbl) { return (0xF64 >> (2 * lbl)) & 3; }

// ---------------- K1: deterministic counting sort by family ----------------
__global__ __launch_bounds__(1024) void sort_kernel(const int* __restrict__ labels,
                                                    int* __restrict__ posOf,
                                                    unsigned char* __restrict__ famSorted,
                                                    int* __restrict__ famLoHi, int B) {
    const int t = threadIdx.x;
    const int lane = t & 63, w = t >> 6;
    int lc[4] = {0, 0, 0, 0};
    int lf[8], lr[8];
#pragma unroll
    for (int j = 0; j < 8; j++) {
        int f = fam_of(labels[t * 8 + j]);
        lf[j] = f; lr[j] = lc[f]++;
    }
    int inc[4];
#pragma unroll
    for (int f = 0; f < 4; f++) {
        int v = lc[f];
#pragma unroll
        for (int o = 1; o < 64; o <<= 1) {
            int u = __shfl_up(v, o, 64);
            if (lane >= o) v += u;
        }
        inc[f] = v;
    }
    __shared__ int waveTot[16][4], waveBase[16][4], famBase[4], famTotS[4];
    if (lane == 63)
#pragma unroll
        for (int f = 0; f < 4; f++) waveTot[w][f] = inc[f];
    __syncthreads();
    if (t < 64) {
        int f = t >> 4, ww = t & 15;
        int v = waveTot[ww][f];
#pragma unroll
        for (int o = 1; o < 16; o <<= 1) {
            int u = __shfl_up(v, o, 64);
            if ((t & 15) >= o) v += u;
        }
        waveBase[ww][f] = v - waveTot[ww][f];
        if (ww == 15) famTotS[f] = v;
    }
    __syncthreads();
    if (t == 0) {
        int b = 0;
#pragma unroll
        for (int f = 0; f < 4; f++) {
            famBase[f] = b; famLoHi[f] = b; b += famTotS[f]; famLoHi[4 + f] = b;
        }
    }
    __syncthreads();
    int base[4];
#pragma unroll
    for (int f = 0; f < 4; f++) base[f] = famBase[f] + waveBase[w][f] + (inc[f] - lc[f]);
#pragma unroll
    for (int j = 0; j < 8; j++) {
        int pos = base[lf[j]] + lr[j];
        posOf[t * 8 + j] = pos;
        famSorted[pos] = (unsigned char)lf[j];
    }
}

// ---------------- K2: normalize + bf16 round + packed scatter (hi only) ----------------
// pack layout: idx = strip*1024 + (k>>3)*128 + (pos&15)*8 + (k&7).
// Fragment read: 16B at strip*1024 + kwin*512 + lane*8. A and B share the map,
// so the MFMA k-contraction is permutation-invariant (absmax-verified R2/R8).
__global__ __launch_bounds__(256) void normpack_kernel(const float* __restrict__ emb,
                                                       const int* __restrict__ posOf,
                                                       short* __restrict__ pack, int B) {
    const int lane = threadIdx.x & 63;
    const int wid  = threadIdx.x >> 6;
    const int row  = blockIdx.x * 4 + wid;
    float x = emb[(size_t)row * 64 + lane];
    float ss = x * x;
#pragma unroll
    for (int o = 32; o > 0; o >>= 1) ss += __shfl_xor(ss, o, 64);
    float n = fmaxf(sqrtf(ss), 1e-12f);
    unsigned short h = f2bf_rne(x / n);
    int pos = posOf[row];
    size_t idx = (size_t)(pos >> 4) * 1024 + (size_t)(lane >> 3) * 128 + (size_t)(pos & 15) * 8 + (lane & 7);
    pack[idx] = (short)h;
}

// ---------------- K3: bf16 MFMA GEMM + lane-local masked min/max ----------------
// SWAPPED OPERANDS (T12 idea): acc = mfma(B_tilefrag, A_rowfrag) puts the
// OUTPUT ROW in lane&15 and the tile's 16 cols in (g=lane>>4, reg 0..3).
// Column min/max is then lane-local (scalar mn[s]/mx[s] per strip); the
// cross-lane reduce is only 2 shfl rounds (xor 16, 32) over 8 values.
__global__ __launch_bounds__(256) void gemm_minmax_kernel(
    const short* __restrict__ pack,
    const unsigned char* __restrict__ famSorted, const int* __restrict__ famLoHi,
    float* __restrict__ pMin, float* __restrict__ pMax, int B) {
    const int lane = threadIdx.x & 63;
    const int wid  = threadIdx.x >> 6;
    const int g = lane >> 4;
    const int c = lane & 15;
    const int rowBase = blockIdx.x * 256 + wid * 64;
    const int aStrip0 = rowBase >> 4;

    // A (row) fragments: 4 strips x 2 k-windows = 32 VGPRs, resident all sweep.
    bf16x8 aH[4][2];
#pragma unroll
    for (int s = 0; s < 4; s++) {
        const short* pA = pack + (size_t)(aStrip0 + s) * 1024;
        aH[s][0] = *(const bf16x8*)(pA + lane * 8);
        aH[s][1] = *(const bf16x8*)(pA + 512 + lane * 8);
    }

    // Per-strip family classification (rows sorted -> piecewise constant).
    int sLo[4], sHi[4], sUni[4];
#pragma unroll
    for (int s = 0; s < 4; s++) {
        int f0  = famSorted[rowBase + s * 16];
        int f15 = famSorted[rowBase + s * 16 + 15];
        sUni[s] = __builtin_amdgcn_readfirstlane((f0 == f15) ? 1 : 0);
        sLo[s]  = __builtin_amdgcn_readfirstlane(famLoHi[f0]);
        sHi[s]  = __builtin_amdgcn_readfirstlane(famLoHi[4 + f0]);
    }

    const f32x4 zq = {0.f, 0.f, 0.f, 0.f};
    float mn[4] = {1e30f, 1e30f, 1e30f, 1e30f};
    float mx[4] = {-1e30f, -1e30f, -1e30f, -1e30f};

    const int jChunk0 = blockIdx.y * 128;
    const int jStrip0 = jChunk0 >> 4;
    const short* pBbase = pack + (size_t)jStrip0 * 1024;

#pragma unroll
    for (int jp = 0; jp < NPAIR; jp++) {
        const int j0 = jChunk0 + jp * 32;
        const short* pB0 = pBbase + (size_t)(2 * jp) * 1024;
        const short* pB1 = pB0 + 1024;
        bf16x8 b0h0 = *(const bf16x8*)(pB0 + lane * 8);
        bf16x8 b0h1 = *(const bf16x8*)(pB0 + 512 + lane * 8);
        bf16x8 b1h0 = *(const bf16x8*)(pB1 + lane * 8);
        bf16x8 b1h1 = *(const bf16x8*)(pB1 + 512 + lane * 8);

#pragma unroll
        for (int s = 0; s < 4; s++) {
            // swapped operands: D[j][i], j=(g,reg) cols, i=lane&15 row
            f32x4 accA, accB;
            accA = __builtin_amdgcn_mfma_f32_16x16x32_bf16(b0h0, aH[s][0], zq, 0, 0, 0);
            accB = __builtin_amdgcn_mfma_f32_16x16x32_bf16(b1h0, aH[s][0], zq, 0, 0, 0);
            accA = __builtin_amdgcn_mfma_f32_16x16x32_bf16(b0h1, aH[s][1], accA, 0, 0, 0);
            accB = __builtin_amdgcn_mfma_f32_16x16x32_bf16(b1h1, aH[s][1], accB, 0, 0, 0);

            if (sUni[s] && j0 >= sLo[s] && j0 + 32 <= sHi[s]) {
                // both tiles fully same-family (diag dot~1 never the min)
                float a01 = fminf(accA[0], accA[1]), a23 = fminf(accA[2], accA[3]);
                float b01 = fminf(accB[0], accB[1]), b23 = fminf(accB[2], accB[3]);
                mn[s] = fminf(mn[s], fminf(fminf(a01, a23), fminf(b01, b23)));
            } else if (sUni[s] && (j0 >= sHi[s] || j0 + 32 <= sLo[s])) {
                // both tiles fully different-family
                float a01 = fmaxf(accA[0], accA[1]), a23 = fmaxf(accA[2], accA[3]);
                float b01 = fmaxf(accB[0], accB[1]), b23 = fmaxf(accB[2], accB[3]);
                mx[s] = fmaxf(mx[s], fmaxf(fmaxf(a01, a23), fmaxf(b01, b23)));
            } else {
                // rare: pair spans a family boundary -> per-element compare
                int fi = famSorted[rowBase + s * 16 + c];   // this lane's row family
                unsigned fjA = *(const unsigned*)(famSorted + j0 + g * 4);
                unsigned fjB = *(const unsigned*)(famSorted + j0 + 16 + g * 4);
#pragma unroll
                for (int r = 0; r < 4; r++) {
                    bool sameA = ((int)((fjA >> (8 * r)) & 255u) == fi);
                    bool sameB = ((int)((fjB >> (8 * r)) & 255u) == fi);
                    mn[s] = fminf(mn[s], sameA ? accA[r] : 1e30f);
                    mx[s] = fmaxf(mx[s], sameA ? -1e30f : accA[r]);
                    mn[s] = fminf(mn[s], sameB ? accB[r] : 1e30f);
                    mx[s] = fmaxf(mx[s], sameB ? -1e30f : accB[r]);
                }
            }
        }
    }

    // Reduce across the 4 g-groups (lanes c, c+16, c+32, c+48): 2 shfl rounds.
#pragma unroll
    for (int s = 0; s < 4; s++) {
        float mnv = mn[s], mxv = mx[s];
        mnv = fminf(mnv, __shfl_xor(mnv, 16, 64));
        mxv = fmaxf(mxv, __shfl_xor(mxv, 16, 64));
        mnv = fminf(mnv, __shfl_xor(mnv, 32, 64));
        mxv = fmaxf(mxv, __shfl_xor(mxv, 32, 64));
        if (g == 0) {
            int row = rowBase + s * 16 + c;  // sorted-row index; 16-lane coalesced
            pMin[(size_t)blockIdx.y * B + row] = mnv;
            pMax[(size_t)blockIdx.y * B + row] = mxv;
        }
    }
}

// ---------------- K4: per-row chunk combine + block partial sums ----------------
__global__ __launch_bounds__(256) void rowloss_kernel(const float* __restrict__ pMin,
                                                      const float* __restrict__ pMax,
                                                      float* __restrict__ partial, int B) {
    const int row = blockIdx.x * 256 + threadIdx.x;
    float mn = 1e30f, mx = -1e30f;
#pragma unroll 8
    for (int cn = 0; cn < NJ; cn++) {
        mn = fminf(mn, pMin[(size_t)cn * B + row]);
        mx = fmaxf(mx, pMax[(size_t)cn * B + row]);
    }
    float sum = 0.f, cnt = 0.f;
    if (mn < 1e29f && mx > -1e29f) {  // has same && has diff
        sum = fmaxf(mx - mn + MARGIN, 0.f);  // relu(d_pos - d_neg + margin)
        cnt = 1.f;
    }
#pragma unroll
    for (int o = 32; o > 0; o >>= 1) {
        sum += __shfl_xor(sum, o, 64);
        cnt += __shfl_xor(cnt, o, 64);
    }
    __shared__ float sS[4], sC[4];
    const int lane = threadIdx.x & 63, w = threadIdx.x >> 6;
    if (lane == 0) { sS[w] = sum; sC[w] = cnt; }
    __syncthreads();
    if (threadIdx.x == 0) {
        partial[blockIdx.x]      = sS[0] + sS[1] + sS[2] + sS[3];
        partial[64 + blockIdx.x] = sC[0] + sC[1] + sC[2] + sC[3];
    }
}

// ---------------- K5: deterministic final reduce ----------------
__global__ void final_kernel(const float* __restrict__ partial, float* __restrict__ out, int nb) {
    if (threadIdx.x == 0) {
        float S = 0.f, C = 0.f;
        for (int i = 0; i < nb; i++) { S += partial[i]; C += partial[64 + i]; }
        out[0] = S / fmaxf(C, 1.f);
    }
}

extern "C" void kernel_launch(void* const* d_in, const int* in_sizes, int n_in,
                              void* d_out, int out_size, void* d_ws, size_t ws_size,
                              hipStream_t stream) {
    const float* emb    = (const float*)d_in[0];
    const int*   labels = (const int*)d_in[1];
    const int B = in_sizes[1];  // 8192, D == 64

    char* base = (char*)d_ws;
    size_t off = 0;
    auto alloc = [&](size_t bytes) -> char* {
        char* p = base + off;
        off = (off + bytes + 255) & ~(size_t)255;
        return p;
    };
    int*           posOf     = (int*)alloc((size_t)B * 4);
    unsigned char* famSorted = (unsigned char*)alloc((size_t)B);
    int*           famLoHi   = (int*)alloc(32);
    short*         pack      = (short*)alloc((size_t)B * 64 * 2);  // hi-only, 1MB
    float*         pMin      = (float*)alloc((size_t)NJ * B * 4);
    float*         pMax      = (float*)alloc((size_t)NJ * B * 4);
    float*         partial   = (float*)alloc(128 * 4);

    sort_kernel<<<1, 1024, 0, stream>>>(labels, posOf, famSorted, famLoHi, B);
    normpack_kernel<<<B / 4, 256, 0, stream>>>(emb, posOf, pack, B);
    dim3 g3(B / 256, NJ);
    gemm_minmax_kernel<<<g3, 256, 0, stream>>>(pack, famSorted, famLoHi, pMin, pMax, B);
    rowloss_kernel<<<B / 256, 256, 0, stream>>>(pMin, pMax, partial, B);
    final_kernel<<<1, 64, 0, stream>>>(partial, (float*)d_out, B / 256);
}

// Round 11
// 33.262 us; speedup vs baseline: 2.9639x; 1.0157x over previous
//
#include <hip/hip_runtime.h>
#include <math.h>

#define MARGIN 0.3f
#define NJ 32        // column chunks; chunk = 256 cols = 8 pairs of 16x2
#define NPAIR 8      // compile-time: (8192/NJ)/32

typedef short bf16x8 __attribute__((ext_vector_type(8)));
typedef float f32x4 __attribute__((ext_vector_type(4)));
typedef unsigned int u32;
typedef const __attribute__((address_space(1))) u32* gp_t;
typedef __attribute__((address_space(3))) u32* lp_t;

__device__ __forceinline__ unsigned short f2bf_rne(float x) {
    unsigned b = __float_as_uint(x);
    unsigned r = b + 0x7FFFu + ((b >> 16) & 1u);
    return (unsigned short)(r >> 16);
}
// family table {0,1,2,1,3,3} packed 2 bits/entry
__device__ __forceinline__ int fam_of(int lbl) { return (0xF64 >> (2 * lbl)) & 3; }

// ---------------- K1: deterministic counting sort by family (+ counter init) ----------------
__global__ __launch_bounds__(1024) void sort_kernel(const int* __restrict__ labels,
                                                    int* __restrict__ posOf,
                                                    unsigned char* __restrict__ famSorted,
                                                    int* __restrict__ famLoHi,
                                                    unsigned* __restrict__ counter, int B) {
    const int t = threadIdx.x;
    const int lane = t & 63, w = t >> 6;
    if (t == 0) *counter = 0;   // re-armed every call (deterministic replays)
    int lc[4] = {0, 0, 0, 0};
    int lf[8], lr[8];
#pragma unroll
    for (int j = 0; j < 8; j++) {
        int f = fam_of(labels[t * 8 + j]);
        lf[j] = f; lr[j] = lc[f]++;
    }
    int inc[4];
#pragma unroll
    for (int f = 0; f < 4; f++) {
        int v = lc[f];
#pragma unroll
        for (int o = 1; o < 64; o <<= 1) {
            int u = __shfl_up(v, o, 64);
            if (lane >= o) v += u;
        }
        inc[f] = v;
    }
    __shared__ int waveTot[16][4], waveBase[16][4], famBase[4], famTotS[4];
    if (lane == 63)
#pragma unroll
        for (int f = 0; f < 4; f++) waveTot[w][f] = inc[f];
    __syncthreads();
    if (t < 64) {
        int f = t >> 4, ww = t & 15;
        int v = waveTot[ww][f];
#pragma unroll
        for (int o = 1; o < 16; o <<= 1) {
            int u = __shfl_up(v, o, 64);
            if ((t & 15) >= o) v += u;
        }
        waveBase[ww][f] = v - waveTot[ww][f];
        if (ww == 15) famTotS[f] = v;
    }
    __syncthreads();
    if (t == 0) {
        int b = 0;
#pragma unroll
        for (int f = 0; f < 4; f++) {
            famBase[f] = b; famLoHi[f] = b; b += famTotS[f]; famLoHi[4 + f] = b;
        }
    }
    __syncthreads();
    int base[4];
#pragma unroll
    for (int f = 0; f < 4; f++) base[f] = famBase[f] + waveBase[w][f] + (inc[f] - lc[f]);
#pragma unroll
    for (int j = 0; j < 8; j++) {
        int pos = base[lf[j]] + lr[j];
        posOf[t * 8 + j] = pos;
        famSorted[pos] = (unsigned char)lf[j];
    }
}

// ---------------- K2: normalize + bf16 round + packed scatter (hi only) ----------------
// pack layout: idx = strip*1024 + (k>>3)*128 + (pos&15)*8 + (k&7).
// Fragment read: 16B at strip*1024 + kwin*512 + lane*8. A and B share the map,
// so the MFMA k-contraction is permutation-invariant (absmax-verified R2/R8).
__global__ __launch_bounds__(256) void normpack_kernel(const float* __restrict__ emb,
                                                       const int* __restrict__ posOf,
                                                       short* __restrict__ pack, int B) {
    const int lane = threadIdx.x & 63;
    const int wid  = threadIdx.x >> 6;
    const int row  = blockIdx.x * 4 + wid;
    float x = emb[(size_t)row * 64 + lane];
    float ss = x * x;
#pragma unroll
    for (int o = 32; o > 0; o >>= 1) ss += __shfl_xor(ss, o, 64);
    float n = fmaxf(sqrtf(ss), 1e-12f);
    unsigned short h = f2bf_rne(x / n);
    int pos = posOf[row];
    size_t idx = (size_t)(pos >> 4) * 1024 + (size_t)(lane >> 3) * 128 + (size_t)(pos & 15) * 8 + (lane & 7);
    pack[idx] = (short)h;
}

// ---------------- K3: LDS-staged bf16 MFMA GEMM + lane-local min/max ----------------
// Block: 256 rows x 256 cols. B chunk (32 KB, fragment-linear) staged ONCE per
// block via global_load_lds and shared by all 4 waves (L2 traffic /4).
// Swapped operands (R10): output row in lane&15, tile cols in (g,reg) ->
// min/max is lane-local; epilogue = 2 shfl rounds.
__global__ __launch_bounds__(256) void gemm_minmax_kernel(
    const short* __restrict__ pack,
    const unsigned char* __restrict__ famSorted, const int* __restrict__ famLoHi,
    float* __restrict__ pMin, float* __restrict__ pMax, int B) {
    __shared__ short ldsB[16384];   // 32 KB

    const int lane = threadIdx.x & 63;
    const int wid  = threadIdx.x >> 6;
    const int g = lane >> 4;
    const int c = lane & 15;
    const int rowBase = blockIdx.x * 256 + wid * 64;
    const int aStrip0 = rowBase >> 4;
    const int jChunk0 = blockIdx.y * 256;
    const int jStrip0 = jChunk0 >> 4;

    // A (row) fragments first (loads in flight during staging issue).
    bf16x8 aH[4][2];
#pragma unroll
    for (int s = 0; s < 4; s++) {
        const short* pA = pack + (size_t)(aStrip0 + s) * 1024;
        aH[s][0] = *(const bf16x8*)(pA + lane * 8);
        aH[s][1] = *(const bf16x8*)(pA + 512 + lane * 8);
    }

    // Stage B chunk: 32 KB linear; each wave 8 KB = 8 x 1KB global_load_lds.
    {
        const char* src = (const char*)(pack + (size_t)jStrip0 * 1024);
#pragma unroll
        for (int i = 0; i < 8; i++) {
            int off = wid * 8192 + i * 1024;
            __builtin_amdgcn_global_load_lds((gp_t)(src + off + lane * 16),
                                             (lp_t)((char*)ldsB + off), 16, 0, 0);
        }
    }

    // Per-strip family classification (rows sorted -> piecewise constant).
    int sLo[4], sHi[4], sUni[4];
#pragma unroll
    for (int s = 0; s < 4; s++) {
        int f0  = famSorted[rowBase + s * 16];
        int f15 = famSorted[rowBase + s * 16 + 15];
        sUni[s] = __builtin_amdgcn_readfirstlane((f0 == f15) ? 1 : 0);
        sLo[s]  = __builtin_amdgcn_readfirstlane(famLoHi[f0]);
        sHi[s]  = __builtin_amdgcn_readfirstlane(famLoHi[4 + f0]);
    }

    const f32x4 zq = {0.f, 0.f, 0.f, 0.f};
    float mn[4] = {1e30f, 1e30f, 1e30f, 1e30f};
    float mx[4] = {-1e30f, -1e30f, -1e30f, -1e30f};

    __syncthreads();   // staging complete (vmcnt drained before barrier)

#pragma unroll
    for (int jp = 0; jp < NPAIR; jp++) {
        const int j0 = jChunk0 + jp * 32;
        const short* pB0 = ldsB + (size_t)(2 * jp) * 1024;
        const short* pB1 = pB0 + 1024;
        bf16x8 b0h0 = *(const bf16x8*)(pB0 + lane * 8);
        bf16x8 b0h1 = *(const bf16x8*)(pB0 + 512 + lane * 8);
        bf16x8 b1h0 = *(const bf16x8*)(pB1 + lane * 8);
        bf16x8 b1h1 = *(const bf16x8*)(pB1 + 512 + lane * 8);

#pragma unroll
        for (int s = 0; s < 4; s++) {
            // swapped operands: D[j][i], j=(g,reg) cols, i=lane&15 row
            f32x4 accA, accB;
            accA = __builtin_amdgcn_mfma_f32_16x16x32_bf16(b0h0, aH[s][0], zq, 0, 0, 0);
            accB = __builtin_amdgcn_mfma_f32_16x16x32_bf16(b1h0, aH[s][0], zq, 0, 0, 0);
            accA = __builtin_amdgcn_mfma_f32_16x16x32_bf16(b0h1, aH[s][1], accA, 0, 0, 0);
            accB = __builtin_amdgcn_mfma_f32_16x16x32_bf16(b1h1, aH[s][1], accB, 0, 0, 0);

            if (sUni[s] && j0 >= sLo[s] && j0 + 32 <= sHi[s]) {
                // both tiles fully same-family (diag dot~1 never the min)
                float a01 = fminf(accA[0], accA[1]), a23 = fminf(accA[2], accA[3]);
                float b01 = fminf(accB[0], accB[1]), b23 = fminf(accB[2], accB[3]);
                mn[s] = fminf(mn[s], fminf(fminf(a01, a23), fminf(b01, b23)));
            } else if (sUni[s] && (j0 >= sHi[s] || j0 + 32 <= sLo[s])) {
                // both tiles fully different-family
                float a01 = fmaxf(accA[0], accA[1]), a23 = fmaxf(accA[2], accA[3]);
                float b01 = fmaxf(accB[0], accB[1]), b23 = fmaxf(accB[2], accB[3]);
                mx[s] = fmaxf(mx[s], fmaxf(fmaxf(a01, a23), fmaxf(b01, b23)));
            } else {
                // rare: pair spans a family boundary -> per-element compare
                int fi = famSorted[rowBase + s * 16 + c];   // this lane's row family
                unsigned fjA = *(const unsigned*)(famSorted + j0 + g * 4);
                unsigned fjB = *(const unsigned*)(famSorted + j0 + 16 + g * 4);
#pragma unroll
                for (int r = 0; r < 4; r++) {
                    bool sameA = ((int)((fjA >> (8 * r)) & 255u) == fi);
                    bool sameB = ((int)((fjB >> (8 * r)) & 255u) == fi);
                    mn[s] = fminf(mn[s], sameA ? accA[r] : 1e30f);
                    mx[s] = fmaxf(mx[s], sameA ? -1e30f : accA[r]);
                    mn[s] = fminf(mn[s], sameB ? accB[r] : 1e30f);
                    mx[s] = fmaxf(mx[s], sameB ? -1e30f : accB[r]);
                }
            }
        }
    }

    // Reduce across the 4 g-groups (lanes c, c+16, c+32, c+48): 2 shfl rounds.
#pragma unroll
    for (int s = 0; s < 4; s++) {
        float mnv = mn[s], mxv = mx[s];
        mnv = fminf(mnv, __shfl_xor(mnv, 16, 64));
        mxv = fmaxf(mxv, __shfl_xor(mxv, 16, 64));
        mnv = fminf(mnv, __shfl_xor(mnv, 32, 64));
        mxv = fmaxf(mxv, __shfl_xor(mxv, 32, 64));
        if (g == 0) {
            int row = rowBase + s * 16 + c;  // sorted-row index; 16-lane coalesced
            pMin[(size_t)blockIdx.y * B + row] = mnv;
            pMax[(size_t)blockIdx.y * B + row] = mxv;
        }
    }
}

// ---------------- K4: per-row combine + partial sums + last-block finalize ----------------
__global__ __launch_bounds__(256) void rowloss_final_kernel(const float* __restrict__ pMin,
                                                            const float* __restrict__ pMax,
                                                            float* __restrict__ partial,
                                                            unsigned* __restrict__ counter,
                                                            float* __restrict__ out, int B) {
    const int nb = B / 256;  // 32 blocks
    const int row = blockIdx.x * 256 + threadIdx.x;
    float mn = 1e30f, mx = -1e30f;
#pragma unroll 8
    for (int cn = 0; cn < NJ; cn++) {
        mn = fminf(mn, pMin[(size_t)cn * B + row]);
        mx = fmaxf(mx, pMax[(size_t)cn * B + row]);
    }
    float sum = 0.f, cnt = 0.f;
    if (mn < 1e29f && mx > -1e29f) {  // has same && has diff
        sum = fmaxf(mx - mn + MARGIN, 0.f);  // relu(d_pos - d_neg + margin)
        cnt = 1.f;
    }
#pragma unroll
    for (int o = 32; o > 0; o >>= 1) {
        sum += __shfl_xor(sum, o, 64);
        cnt += __shfl_xor(cnt, o, 64);
    }
    __shared__ float sS[4], sC[4];
    const int lane = threadIdx.x & 63, w = threadIdx.x >> 6;
    if (lane == 0) { sS[w] = sum; sC[w] = cnt; }
    __syncthreads();
    if (threadIdx.x == 0) {
        partial[blockIdx.x]      = sS[0] + sS[1] + sS[2] + sS[3];
        partial[64 + blockIdx.x] = sC[0] + sC[1] + sC[2] + sC[3];
        __threadfence();
        unsigned done = atomicAdd(counter, 1u);
        if (done == (unsigned)(nb - 1)) {   // last block finalizes
            __threadfence();
            float S = 0.f, C = 0.f;
            for (int i = 0; i < nb; i++) { S += partial[i]; C += partial[64 + i]; }
            out[0] = S / fmaxf(C, 1.f);
        }
    }
}

extern "C" void kernel_launch(void* const* d_in, const int* in_sizes, int n_in,
                              void* d_out, int out_size, void* d_ws, size_t ws_size,
                              hipStream_t stream) {
    const float* emb    = (const float*)d_in[0];
    const int*   labels = (const int*)d_in[1];
    const int B = in_sizes[1];  // 8192, D == 64

    char* base = (char*)d_ws;
    size_t off = 0;
    auto alloc = [&](size_t bytes) -> char* {
        char* p = base + off;
        off = (off + bytes + 255) & ~(size_t)255;
        return p;
    };
    int*           posOf     = (int*)alloc((size_t)B * 4);
    unsigned char* famSorted = (unsigned char*)alloc((size_t)B);
    int*           famLoHi   = (int*)alloc(32);
    unsigned*      counter   = (unsigned*)alloc(64);
    short*         pack      = (short*)alloc((size_t)B * 64 * 2);  // hi-only, 1MB
    float*         pMin      = (float*)alloc((size_t)NJ * B * 4);
    float*         pMax      = (float*)alloc((size_t)NJ * B * 4);
    float*         partial   = (float*)alloc(128 * 4);

    sort_kernel<<<1, 1024, 0, stream>>>(labels, posOf, famSorted, famLoHi, counter, B);
    normpack_kernel<<<B / 4, 256, 0, stream>>>(emb, posOf, pack, B);
    dim3 g3(B / 256, NJ);
    gemm_minmax_kernel<<<g3, 256, 0, stream>>>(pack, famSorted, famLoHi, pMin, pMax, B);
    rowloss_final_kernel<<<B / 256, 256, 0, stream>>>(pMin, pMax, partial, counter,
                                                      (float*)d_out, B);
}